// Round 2
// baseline (527.988 us; speedup 1.0000x reference)
//
#include <hip/hip_runtime.h>
#include <math.h>

#define S_LEN 2064
#define NB 2
#define NH 9
#define NKV 3
#define HD 64
#define EMB 576
#define NTOK (NB*S_LEN)          // 4128
#define LSTR 68                  // padded LDS stride (floats), 16B-aligned

#define QSZ (NB*NH*S_LEN*HD)     // 2377728
#define KSZ (NB*NKV*S_LEN*HD)    // 792576
#define VSZ (NB*NKV*S_LEN*HD)    // 792576
#define ASZ (NB*S_LEN*EMB)       // 2377728

// ---------------------------------------------------------------------------
// Fused QKV/Qr/Kr projection: y = x @ Wcat^T, scattered into Q/K/V buffers.
// Q: (b,9,s,64) cols 0..55 main, 56..63 rope(raw). K: (b,3,s,64). V: (b,3,s,64)
// ---------------------------------------------------------------------------
__global__ __launch_bounds__(256)
void proj_kernel(const float* __restrict__ x,
                 const float* __restrict__ qw, const float* __restrict__ kw,
                 const float* __restrict__ vw, const float* __restrict__ qrw,
                 const float* __restrict__ krw,
                 float* __restrict__ Qb, float* __restrict__ Kb,
                 float* __restrict__ Vb) {
  __shared__ float Xs[16*LSTR];
  __shared__ float Ws[16*LSTR];
  const int tid = threadIdx.x;
  const int tx = tid & 15, ty = tid >> 4;
  const int m0 = blockIdx.x * 64;
  const int n0 = blockIdx.y * 64;

  // staging assignment: thread t stages row/col (t>>2), k-offset (t&3)*4
  const int sr = tid >> 2;
  const int kq = (tid & 3) * 4;
  int gm = m0 + sr; if (gm > NTOK-1) gm = NTOK-1;
  const float* xrow = x + (size_t)gm * EMB;
  const int col = n0 + sr;
  const float* wrow;
  if (col < 504)      wrow = qw  + (size_t)col       * EMB;
  else if (col < 672) wrow = kw  + (size_t)(col-504) * EMB;
  else if (col < 864) wrow = vw  + (size_t)(col-672) * EMB;
  else if (col < 936) wrow = qrw + (size_t)(col-864) * EMB;
  else                wrow = krw + (size_t)(col-936) * EMB;

  float acc[4][4];
  #pragma unroll
  for (int i=0;i<4;++i)
    #pragma unroll
    for (int j=0;j<4;++j) acc[i][j]=0.f;

  for (int kc = 0; kc < EMB; kc += 16) {
    __syncthreads();
    float4 xa = *(const float4*)(xrow + kc + kq);
    float4 wa = *(const float4*)(wrow + kc + kq);
    Xs[(kq+0)*LSTR + sr] = xa.x;
    Xs[(kq+1)*LSTR + sr] = xa.y;
    Xs[(kq+2)*LSTR + sr] = xa.z;
    Xs[(kq+3)*LSTR + sr] = xa.w;
    Ws[(kq+0)*LSTR + sr] = wa.x;
    Ws[(kq+1)*LSTR + sr] = wa.y;
    Ws[(kq+2)*LSTR + sr] = wa.z;
    Ws[(kq+3)*LSTR + sr] = wa.w;
    __syncthreads();
    #pragma unroll
    for (int kk=0; kk<16; ++kk) {
      float4 a  = *(const float4*)(Xs + kk*LSTR + 4*ty);
      float4 bq = *(const float4*)(Ws + kk*LSTR + 4*tx);
      float av[4] = {a.x,a.y,a.z,a.w};
      float bv[4] = {bq.x,bq.y,bq.z,bq.w};
      #pragma unroll
      for (int i=0;i<4;++i)
        #pragma unroll
        for (int j=0;j<4;++j)
          acc[i][j] = fmaf(av[i], bv[j], acc[i][j]);
    }
  }

  #pragma unroll
  for (int i=0;i<4;++i) {
    const int r = m0 + 4*ty + i;
    if (r >= NTOK) break;
    const int b = r / S_LEN, s = r % S_LEN;
    #pragma unroll
    for (int j=0;j<4;++j) {
      const int c = n0 + 4*tx + j;
      const float v = acc[i][j];
      if (c < 504) {
        int h = c / 56, d = c % 56;
        Qb[(((size_t)(b*NH+h))*S_LEN + s)*HD + d] = v;
      } else if (c < 672) {
        int h = (c-504)/56, d = (c-504)%56;
        Kb[(((size_t)(b*NKV+h))*S_LEN + s)*HD + d] = v;
      } else if (c < 864) {
        int h = (c-672)/64, d = (c-672)%64;
        Vb[(((size_t)(b*NKV+h))*S_LEN + s)*HD + d] = v;
      } else if (c < 936) {
        int h = (c-864)/8, d = 56 + (c-864)%8;
        Qb[(((size_t)(b*NH+h))*S_LEN + s)*HD + d] = v;
      } else {
        int h = (c-936)/8, d = 56 + (c-936)%8;
        Kb[(((size_t)(b*NKV+h))*S_LEN + s)*HD + d] = v;
      }
    }
  }
}

// ---------------------------------------------------------------------------
// In-place partial RoPE on dims 56..63 of Q (9 heads) and K (3 heads).
// theta exponents from reference idxs [0,1,16,17] -> {0, 2, 32, 34}/64
// ---------------------------------------------------------------------------
__global__ void rope_kernel(float* __restrict__ Qb, float* __restrict__ Kb) {
  const int idx = blockIdx.x * blockDim.x + threadIdx.x;
  const int total = NB*(NH+NKV)*S_LEN;
  if (idx >= total) return;
  const int s  = idx % S_LEN;
  const int bh = idx / S_LEN;                 // 0..23
  const int b  = bh / (NH+NKV), hh = bh % (NH+NKV);
  float* base;
  if (hh < NH) base = Qb + (((size_t)(b*NH + hh))*S_LEN + s)*HD + 56;
  else         base = Kb + (((size_t)(b*NKV + (hh-NH)))*S_LEN + s)*HD + 56;

  float4 a = *(const float4*)(base);
  float4 c = *(const float4*)(base + 4);
  float xv[8] = {a.x,a.y,a.z,a.w,c.x,c.y,c.z,c.w};
  const float es[4] = {0.0f, 2.0f/64.0f, 32.0f/64.0f, 34.0f/64.0f};
  const float ps = (float)s;
  float o[8];
  #pragma unroll
  for (int j=0;j<4;++j) {
    float th  = 1.0f / powf(100000.0f, es[j]);
    float ang = ps * th;
    float cs = cosf(ang), sn = sinf(ang);
    o[j]   = xv[j]*cs   - xv[j+4]*sn;   // x1*cos + (-x2)*sin
    o[j+4] = xv[j+4]*cs + xv[j]*sn;     // x2*cos + ( x1)*sin
  }
  *(float4*)(base)     = make_float4(o[0],o[1],o[2],o[3]);
  *(float4*)(base + 4) = make_float4(o[4],o[5],o[6],o[7]);
}

// ---------------------------------------------------------------------------
// 2-bit fake-quant of K: per (b,kvh, 64-token group, dim), first 2048 tokens.
// One wave per group; lane = dim; min/max over 64 tokens kept in registers.
// ---------------------------------------------------------------------------
__global__ void quant_key_kernel(float* __restrict__ Kb) {
  const int wid  = (blockIdx.x * blockDim.x + threadIdx.x) >> 6;
  const int lane = threadIdx.x & 63;
  if (wid >= NB*NKV*32) return;              // 2048/64 = 32 groups
  const int bkh = wid >> 5, sg = wid & 31;
  float* base = Kb + ((size_t)bkh*S_LEN + sg*64)*HD + lane;
  float vals[64];
  float mn = 1e30f, mx = -1e30f;
  #pragma unroll
  for (int s=0;s<64;++s) {
    float v = fminf(fmaxf(base[s*HD], -10000.0f), 10000.0f);
    vals[s] = v;
    mn = fminf(mn, v); mx = fmaxf(mx, v);
  }
  float scale = (mx - mn) / 3.0f;
  if (scale == 0.0f) scale = 1.0f;
  #pragma unroll
  for (int s=0;s<64;++s) {
    float q = rintf((vals[s] - mn) / scale);
    base[s*HD] = q * scale + mn;
  }
}

// ---------------------------------------------------------------------------
// 2-bit fake-quant of V: per token over d=64, first 2032 tokens. Wave/token.
// ---------------------------------------------------------------------------
__global__ void quant_value_kernel(float* __restrict__ Vb) {
  const int wid  = (blockIdx.x * blockDim.x + threadIdx.x) >> 6;
  const int lane = threadIdx.x & 63;
  const int total = NB*NKV*2032;
  if (wid >= total) return;
  const int bkh = wid / 2032, s = wid % 2032;
  float* p = Vb + ((size_t)bkh*S_LEN + s)*HD + lane;
  float v = fminf(fmaxf(*p, -10000.0f), 10000.0f);
  float mn = v, mx = v;
  #pragma unroll
  for (int m=1;m<64;m<<=1) {
    mn = fminf(mn, __shfl_xor(mn, m));
    mx = fmaxf(mx, __shfl_xor(mx, m));
  }
  float scale = (mx - mn) / 3.0f;
  if (scale == 0.0f) scale = 1.0f;
  float q = rintf((v - mn) / scale);
  *p = q * scale + mn;
}

// ---------------------------------------------------------------------------
// Flash attention, causal, GQA 3:1. 64x64 tiles, f32, online softmax.
// P reuses the K LDS buffer. Output -> A buffer (b, s, h*64+d).
// ---------------------------------------------------------------------------
__global__ __launch_bounds__(256)
void attn_kernel(const float* __restrict__ Q, const float* __restrict__ K,
                 const float* __restrict__ V, float* __restrict__ A) {
  __shared__ float Qs[64*LSTR];    // [d][row]
  __shared__ float KPs[64*LSTR];   // K: [d][col]; reused as P: [row][col]
  __shared__ float Vs[64*LSTR];    // [k][dim]
  const int tid = threadIdx.x;
  const int tx = tid & 15, ty = tid >> 4;
  const int qt = (int)gridDim.x - 1 - (int)blockIdx.x;   // heavy tiles first
  const int bh = blockIdx.y;
  const int b = bh / NH, h = bh % NH, kvh = h / (NH/NKV);
  const float* Qg = Q + ((size_t)(b*NH + h  )*S_LEN)*HD;
  const float* Kg = K + ((size_t)(b*NKV+ kvh)*S_LEN)*HD;
  const float* Vg = V + ((size_t)(b*NKV+ kvh)*S_LEN)*HD;
  const int qbase = qt * 64;

  {  // stage Q tile transposed [d][row]
    const int r = tid >> 2, dq = (tid & 3) * 4;
    int gr = qbase + r; if (gr > S_LEN-1) gr = S_LEN-1;
    const float* src = Qg + (size_t)gr*HD;
    #pragma unroll
    for (int it=0; it<4; ++it) {
      float4 a = *(const float4*)(src + dq + 16*it);
      Qs[(dq+16*it+0)*LSTR + r] = a.x;
      Qs[(dq+16*it+1)*LSTR + r] = a.y;
      Qs[(dq+16*it+2)*LSTR + r] = a.z;
      Qs[(dq+16*it+3)*LSTR + r] = a.w;
    }
  }

  float acc[4][4];
  #pragma unroll
  for (int i=0;i<4;++i)
    #pragma unroll
    for (int j=0;j<4;++j) acc[i][j]=0.f;
  float m_i[4], l_i[4];
  #pragma unroll
  for (int i=0;i<4;++i) { m_i[i] = -INFINITY; l_i[i] = 0.f; }

  const int nkt = qt + 1;
  for (int kt=0; kt<nkt; ++kt) {
    const int kbase = kt * 64;
    __syncthreads();   // prev PV reads done before restaging
    {
      const int r = tid >> 2, dq = (tid & 3) * 4;
      int gr = kbase + r; if (gr > S_LEN-1) gr = S_LEN-1;
      const float* ksrc = Kg + (size_t)gr*HD;
      const float* vsrc = Vg + (size_t)gr*HD;
      #pragma unroll
      for (int it=0; it<4; ++it) {
        float4 a = *(const float4*)(ksrc + dq + 16*it);
        KPs[(dq+16*it+0)*LSTR + r] = a.x;
        KPs[(dq+16*it+1)*LSTR + r] = a.y;
        KPs[(dq+16*it+2)*LSTR + r] = a.z;
        KPs[(dq+16*it+3)*LSTR + r] = a.w;
        float4 vv = *(const float4*)(vsrc + dq + 16*it);
        *(float4*)(Vs + r*LSTR + dq + 16*it) = vv;
      }
    }
    __syncthreads();

    float sc[4][4];
    #pragma unroll
    for (int i=0;i<4;++i)
      #pragma unroll
      for (int j=0;j<4;++j) sc[i][j]=0.f;
    #pragma unroll 8
    for (int kk=0; kk<64; ++kk) {
      float4 a  = *(const float4*)(Qs  + kk*LSTR + 4*ty);
      float4 bq = *(const float4*)(KPs + kk*LSTR + 4*tx);
      float av[4] = {a.x,a.y,a.z,a.w};
      float bv[4] = {bq.x,bq.y,bq.z,bq.w};
      #pragma unroll
      for (int i=0;i<4;++i)
        #pragma unroll
        for (int j=0;j<4;++j)
          sc[i][j] = fmaf(av[i], bv[j], sc[i][j]);
    }

    const bool diag = (kt == qt);
    float p[4][4], al[4];
    #pragma unroll
    for (int i=0;i<4;++i) {
      #pragma unroll
      for (int j=0;j<4;++j) {
        float sv = sc[i][j] * 0.125f;
        if (diag && (kbase + 4*tx + j > qbase + 4*ty + i)) sv = -INFINITY;
        sc[i][j] = sv;
      }
      float rm = fmaxf(fmaxf(sc[i][0],sc[i][1]), fmaxf(sc[i][2],sc[i][3]));
      rm = fmaxf(rm, __shfl_xor(rm, 1));
      rm = fmaxf(rm, __shfl_xor(rm, 2));
      rm = fmaxf(rm, __shfl_xor(rm, 4));
      rm = fmaxf(rm, __shfl_xor(rm, 8));
      const float mn = fmaxf(m_i[i], rm);
      const float a  = expf(m_i[i] - mn);     // exp(-inf)=0 first tile
      float sum = 0.f;
      #pragma unroll
      for (int j=0;j<4;++j) {
        float pv = expf(sc[i][j] - mn);       // -inf -> 0
        p[i][j] = pv;
        sum += pv;
      }
      sum += __shfl_xor(sum, 1);
      sum += __shfl_xor(sum, 2);
      sum += __shfl_xor(sum, 4);
      sum += __shfl_xor(sum, 8);
      l_i[i] = l_i[i]*a + sum;
      m_i[i] = mn;
      al[i]  = a;
    }
    __syncthreads();   // score reads of KPs complete
    #pragma unroll
    for (int i=0;i<4;++i) {
      *(float4*)(KPs + (4*ty+i)*LSTR + 4*tx) = make_float4(p[i][0],p[i][1],p[i][2],p[i][3]);
      acc[i][0]*=al[i]; acc[i][1]*=al[i]; acc[i][2]*=al[i]; acc[i][3]*=al[i];
    }
    __syncthreads();
    #pragma unroll 8
    for (int kk=0; kk<64; ++kk) {
      float4 vv = *(const float4*)(Vs + kk*LSTR + 4*tx);
      float vvv[4] = {vv.x,vv.y,vv.z,vv.w};
      float pr[4];
      #pragma unroll
      for (int i=0;i<4;++i) pr[i] = KPs[(4*ty+i)*LSTR + kk];
      #pragma unroll
      for (int i=0;i<4;++i)
        #pragma unroll
        for (int j=0;j<4;++j)
          acc[i][j] = fmaf(pr[i], vvv[j], acc[i][j]);
    }
  }

  #pragma unroll
  for (int i=0;i<4;++i) {
    const int r = qbase + 4*ty + i;
    if (r < S_LEN) {
      const float inv = 1.0f / l_i[i];
      float4 o = make_float4(acc[i][0]*inv, acc[i][1]*inv, acc[i][2]*inv, acc[i][3]*inv);
      *(float4*)(A + ((size_t)(b*S_LEN + r))*EMB + h*HD + 4*tx) = o;
    }
  }
}

// ---------------------------------------------------------------------------
// Output projection: out = A @ o_w^T   (M=4128, N=576, K=576)
// ---------------------------------------------------------------------------
__global__ __launch_bounds__(256)
void oproj_kernel(const float* __restrict__ A, const float* __restrict__ ow,
                  float* __restrict__ out) {
  __shared__ float Xs[16*LSTR];
  __shared__ float Ws[16*LSTR];
  const int tid = threadIdx.x;
  const int tx = tid & 15, ty = tid >> 4;
  const int m0 = blockIdx.x * 64;
  const int n0 = blockIdx.y * 64;
  const int sr = tid >> 2;
  const int kq = (tid & 3) * 4;
  int gm = m0 + sr; if (gm > NTOK-1) gm = NTOK-1;
  const float* xrow = A  + (size_t)gm * EMB;
  const float* wrow = ow + (size_t)(n0 + sr) * EMB;

  float acc[4][4];
  #pragma unroll
  for (int i=0;i<4;++i)
    #pragma unroll
    for (int j=0;j<4;++j) acc[i][j]=0.f;

  for (int kc = 0; kc < EMB; kc += 16) {
    __syncthreads();
    float4 xa = *(const float4*)(xrow + kc + kq);
    float4 wa = *(const float4*)(wrow + kc + kq);
    Xs[(kq+0)*LSTR + sr] = xa.x;
    Xs[(kq+1)*LSTR + sr] = xa.y;
    Xs[(kq+2)*LSTR + sr] = xa.z;
    Xs[(kq+3)*LSTR + sr] = xa.w;
    Ws[(kq+0)*LSTR + sr] = wa.x;
    Ws[(kq+1)*LSTR + sr] = wa.y;
    Ws[(kq+2)*LSTR + sr] = wa.z;
    Ws[(kq+3)*LSTR + sr] = wa.w;
    __syncthreads();
    #pragma unroll
    for (int kk=0; kk<16; ++kk) {
      float4 a  = *(const float4*)(Xs + kk*LSTR + 4*ty);
      float4 bq = *(const float4*)(Ws + kk*LSTR + 4*tx);
      float av[4] = {a.x,a.y,a.z,a.w};
      float bv[4] = {bq.x,bq.y,bq.z,bq.w};
      #pragma unroll
      for (int i=0;i<4;++i)
        #pragma unroll
        for (int j=0;j<4;++j)
          acc[i][j] = fmaf(av[i], bv[j], acc[i][j]);
    }
  }

  #pragma unroll
  for (int i=0;i<4;++i) {
    const int r = m0 + 4*ty + i;
    if (r >= NTOK) break;
    *(float4*)(out + (size_t)r*EMB + n0 + 4*tx) =
        make_float4(acc[i][0],acc[i][1],acc[i][2],acc[i][3]);
  }
}

// ---------------------------------------------------------------------------
extern "C" void kernel_launch(void* const* d_in, const int* in_sizes, int n_in,
                              void* d_out, int out_size, void* d_ws, size_t ws_size,
                              hipStream_t stream) {
  const float* x   = (const float*)d_in[0];
  const float* qw  = (const float*)d_in[1];
  const float* kw  = (const float*)d_in[2];
  const float* vw  = (const float*)d_in[3];
  const float* qrw = (const float*)d_in[4];
  const float* krw = (const float*)d_in[5];
  const float* ow  = (const float*)d_in[6];
  float* out = (float*)d_out;

  float* ws = (float*)d_ws;
  float* Qb = ws;
  float* Kb = Qb + QSZ;
  float* Vb = Kb + KSZ;
  float* Ab = Vb + VSZ;

  // 1. fused projections
  dim3 g1((NTOK + 63)/64, 960/64);            // 65 x 15
  proj_kernel<<<g1, 256, 0, stream>>>(x, qw, kw, vw, qrw, krw, Qb, Kb, Vb);

  // 2. rope on q_r / k_r
  {
    int total = NB*(NH+NKV)*S_LEN;
    rope_kernel<<<(total+255)/256, 256, 0, stream>>>(Qb, Kb);
  }

  // 3. fake-quant K (first 2048) and V (first 2032)
  {
    int kwaves = NB*NKV*32;                    // 192 waves
    quant_key_kernel<<<(kwaves*64+255)/256, 256, 0, stream>>>(Kb);
    int vwaves = NB*NKV*2032;                  // 12192 waves
    quant_value_kernel<<<(vwaves*64+255)/256, 256, 0, stream>>>(Vb);
  }

  // 4. causal flash attention
  dim3 ga((S_LEN+63)/64, NB*NH);               // 33 x 18
  attn_kernel<<<ga, 256, 0, stream>>>(Qb, Kb, Vb, Ab);

  // 5. output projection
  dim3 go((NTOK + 63)/64, EMB/64);             // 65 x 9
  oproj_kernel<<<go, 256, 0, stream>>>(Ab, ow, out);
}

// Round 7
// 315.015 us; speedup vs baseline: 1.6761x; 1.6761x over previous
//
#include <hip/hip_runtime.h>
#include <math.h>

#define S_LEN 2064
#define S_PAD 2112               // 33 tiles * 64, zero-padded packed KV
#define NB 2
#define NH 9
#define NKV 3
#define HD 64
#define EMB 576
#define NTOK (NB*S_LEN)          // 4128
#define LSTR 68                  // padded f32 LDS stride
#define KSTR 72                  // bf16 LDS stride: 144B rows -> bank-balanced b128 reads

#define QSZ (NB*NH*S_LEN*HD)     // 2377728
#define KSZ (NB*NKV*S_LEN*HD)    // 792576
#define VSZ (NB*NKV*S_LEN*HD)    // 792576
#define ASZ (NB*S_LEN*EMB)       // 2377728
#define KPK (NB*NKV*S_PAD*HD)    // 811008 (per packed buffer, ushorts)

typedef float  f32x4  __attribute__((ext_vector_type(4)));
typedef short  s16x8  __attribute__((ext_vector_type(8)));

// f32 <-> bf16 (RNE), bit-level
static __device__ __forceinline__ ushort f2bf(float x) {
  union { float f; unsigned u; } a; a.f = x;
  unsigned r = a.u + 0x7fffu + ((a.u >> 16) & 1u);
  return (ushort)(r >> 16);
}
static __device__ __forceinline__ float bf2f(ushort h) {
  union { unsigned u; float f; } a; a.u = ((unsigned)h) << 16;
  return a.f;
}

// ---------------------------------------------------------------------------
// Fused QKV/Qr/Kr projection (f32 SGEMM — kept f32 to protect quant boundary)
// ---------------------------------------------------------------------------
__global__ __launch_bounds__(256)
void proj_kernel(const float* __restrict__ x,
                 const float* __restrict__ qw, const float* __restrict__ kw,
                 const float* __restrict__ vw, const float* __restrict__ qrw,
                 const float* __restrict__ krw,
                 float* __restrict__ Qb, float* __restrict__ Kb,
                 float* __restrict__ Vb) {
  __shared__ float Xs[16*LSTR];
  __shared__ float Ws[16*LSTR];
  const int tid = threadIdx.x;
  const int tx = tid & 15, ty = tid >> 4;
  const int m0 = blockIdx.x * 64;
  const int n0 = blockIdx.y * 64;

  const int sr = tid >> 2;
  const int kq = (tid & 3) * 4;
  int gm = m0 + sr; if (gm > NTOK-1) gm = NTOK-1;
  const float* xrow = x + (size_t)gm * EMB;
  const int col = n0 + sr;
  const float* wrow;
  if (col < 504)      wrow = qw  + (size_t)col       * EMB;
  else if (col < 672) wrow = kw  + (size_t)(col-504) * EMB;
  else if (col < 864) wrow = vw  + (size_t)(col-672) * EMB;
  else if (col < 936) wrow = qrw + (size_t)(col-864) * EMB;
  else                wrow = krw + (size_t)(col-936) * EMB;

  float acc[4][4];
  #pragma unroll
  for (int i=0;i<4;++i)
    #pragma unroll
    for (int j=0;j<4;++j) acc[i][j]=0.f;

  for (int kc = 0; kc < EMB; kc += 16) {
    __syncthreads();
    float4 xa = *(const float4*)(xrow + kc + kq);
    float4 wa = *(const float4*)(wrow + kc + kq);
    Xs[(kq+0)*LSTR + sr] = xa.x;
    Xs[(kq+1)*LSTR + sr] = xa.y;
    Xs[(kq+2)*LSTR + sr] = xa.z;
    Xs[(kq+3)*LSTR + sr] = xa.w;
    Ws[(kq+0)*LSTR + sr] = wa.x;
    Ws[(kq+1)*LSTR + sr] = wa.y;
    Ws[(kq+2)*LSTR + sr] = wa.z;
    Ws[(kq+3)*LSTR + sr] = wa.w;
    __syncthreads();
    #pragma unroll
    for (int kk=0; kk<16; ++kk) {
      float4 a  = *(const float4*)(Xs + kk*LSTR + 4*ty);
      float4 bq = *(const float4*)(Ws + kk*LSTR + 4*tx);
      float av[4] = {a.x,a.y,a.z,a.w};
      float bv[4] = {bq.x,bq.y,bq.z,bq.w};
      #pragma unroll
      for (int i=0;i<4;++i)
        #pragma unroll
        for (int j=0;j<4;++j)
          acc[i][j] = fmaf(av[i], bv[j], acc[i][j]);
    }
  }

  #pragma unroll
  for (int i=0;i<4;++i) {
    const int r = m0 + 4*ty + i;
    if (r >= NTOK) break;
    const int b = r / S_LEN, s = r % S_LEN;
    #pragma unroll
    for (int j=0;j<4;++j) {
      const int c = n0 + 4*tx + j;
      const float v = acc[i][j];
      if (c < 504) {
        int h = c / 56, d = c % 56;
        Qb[(((size_t)(b*NH+h))*S_LEN + s)*HD + d] = v;
      } else if (c < 672) {
        int h = (c-504)/56, d = (c-504)%56;
        Kb[(((size_t)(b*NKV+h))*S_LEN + s)*HD + d] = v;
      } else if (c < 864) {
        int h = (c-672)/64, d = (c-672)%64;
        Vb[(((size_t)(b*NKV+h))*S_LEN + s)*HD + d] = v;
      } else if (c < 936) {
        int h = (c-864)/8, d = 56 + (c-864)%8;
        Qb[(((size_t)(b*NH+h))*S_LEN + s)*HD + d] = v;
      } else {
        int h = (c-936)/8, d = 56 + (c-936)%8;
        Kb[(((size_t)(b*NKV+h))*S_LEN + s)*HD + d] = v;
      }
    }
  }
}

// ---------------------------------------------------------------------------
// In-place partial RoPE on dims 56..63 of Q (9 heads) and K (3 heads).
// ---------------------------------------------------------------------------
__global__ void rope_kernel(float* __restrict__ Qb, float* __restrict__ Kb) {
  const int idx = blockIdx.x * blockDim.x + threadIdx.x;
  const int total = NB*(NH+NKV)*S_LEN;
  if (idx >= total) return;
  const int s  = idx % S_LEN;
  const int bh = idx / S_LEN;
  const int b  = bh / (NH+NKV), hh = bh % (NH+NKV);
  float* base;
  if (hh < NH) base = Qb + (((size_t)(b*NH + hh))*S_LEN + s)*HD + 56;
  else         base = Kb + (((size_t)(b*NKV + (hh-NH)))*S_LEN + s)*HD + 56;

  float4 a = *(const float4*)(base);
  float4 c = *(const float4*)(base + 4);
  float xv[8] = {a.x,a.y,a.z,a.w,c.x,c.y,c.z,c.w};
  const float es[4] = {0.0f, 2.0f/64.0f, 32.0f/64.0f, 34.0f/64.0f};
  const float ps = (float)s;
  float o[8];
  #pragma unroll
  for (int j=0;j<4;++j) {
    float th  = 1.0f / powf(100000.0f, es[j]);
    float ang = ps * th;
    float cs = cosf(ang), sn = sinf(ang);
    o[j]   = xv[j]*cs   - xv[j+4]*sn;
    o[j+4] = xv[j+4]*cs + xv[j]*sn;
  }
  *(float4*)(base)     = make_float4(o[0],o[1],o[2],o[3]);
  *(float4*)(base + 4) = make_float4(o[4],o[5],o[6],o[7]);
}

// ---------------------------------------------------------------------------
// 2-bit fake-quant of K (per 64-token group per dim, first 2048 tokens)
// ---------------------------------------------------------------------------
__global__ void quant_key_kernel(float* __restrict__ Kb) {
  const int wid  = (blockIdx.x * blockDim.x + threadIdx.x) >> 6;
  const int lane = threadIdx.x & 63;
  if (wid >= NB*NKV*32) return;
  const int bkh = wid >> 5, sg = wid & 31;
  float* base = Kb + ((size_t)bkh*S_LEN + sg*64)*HD + lane;
  float vals[64];
  float mn = 1e30f, mx = -1e30f;
  #pragma unroll
  for (int s=0;s<64;++s) {
    float v = fminf(fmaxf(base[s*HD], -10000.0f), 10000.0f);
    vals[s] = v;
    mn = fminf(mn, v); mx = fmaxf(mx, v);
  }
  float scale = (mx - mn) / 3.0f;
  if (scale == 0.0f) scale = 1.0f;
  #pragma unroll
  for (int s=0;s<64;++s) {
    float q = rintf((vals[s] - mn) / scale);
    base[s*HD] = q * scale + mn;
  }
}

// ---------------------------------------------------------------------------
// 2-bit fake-quant of V (per token over d=64, first 2032 tokens)
// ---------------------------------------------------------------------------
__global__ void quant_value_kernel(float* __restrict__ Vb) {
  const int wid  = (blockIdx.x * blockDim.x + threadIdx.x) >> 6;
  const int lane = threadIdx.x & 63;
  const int total = NB*NKV*2032;
  if (wid >= total) return;
  const int bkh = wid / 2032, s = wid % 2032;
  float* p = Vb + ((size_t)bkh*S_LEN + s)*HD + lane;
  float v = fminf(fmaxf(*p, -10000.0f), 10000.0f);
  float mn = v, mx = v;
  #pragma unroll
  for (int m=1;m<64;m<<=1) {
    mn = fminf(mn, __shfl_xor(mn, m));
    mx = fmaxf(mx, __shfl_xor(mx, m));
  }
  float scale = (mx - mn) / 3.0f;
  if (scale == 0.0f) scale = 1.0f;
  float q = rintf((v - mn) / scale);
  *p = q * scale + mn;
}

// ---------------------------------------------------------------------------
// Pack K (post-rope, post-quant) -> global bf16 hi/lo [bkv][S_PAD][64],
// zero-padded rows >= S_LEN. One thread per 8-dim segment.
// ---------------------------------------------------------------------------
__global__ __launch_bounds__(256)
void pack_k_kernel(const float* __restrict__ Kb,
                   ushort* __restrict__ KhiG, ushort* __restrict__ KloG) {
  const int idx = blockIdx.x * blockDim.x + threadIdx.x;
  const int total = NB*NKV*S_PAD*8;
  if (idx >= total) return;
  const int bkv = idx / (S_PAD*8);
  const int rem = idx % (S_PAD*8);
  const int s = rem >> 3, d0 = (rem & 7) * 8;
  uint u_h[4], u_l[4];
  if (s < S_LEN) {
    const float* src = Kb + ((size_t)bkv*S_LEN + s)*HD + d0;
    float4 a = *(const float4*)(src);
    float4 b = *(const float4*)(src + 4);
    float v[8] = {a.x,a.y,a.z,a.w,b.x,b.y,b.z,b.w};
    ushort hb[8], lb[8];
    #pragma unroll
    for (int e=0;e<8;++e) {
      hb[e] = f2bf(v[e]);
      lb[e] = f2bf(v[e] - bf2f(hb[e]));
    }
    #pragma unroll
    for (int m=0;m<4;++m) {
      u_h[m] = (uint)hb[2*m] | ((uint)hb[2*m+1] << 16);
      u_l[m] = (uint)lb[2*m] | ((uint)lb[2*m+1] << 16);
    }
  } else {
    #pragma unroll
    for (int m=0;m<4;++m) { u_h[m] = 0; u_l[m] = 0; }
  }
  const size_t off = ((size_t)bkv*S_PAD + s)*HD + d0;
  *(uint4*)(KhiG + off) = make_uint4(u_h[0],u_h[1],u_h[2],u_h[3]);
  *(uint4*)(KloG + off) = make_uint4(u_l[0],u_l[1],u_l[2],u_l[3]);
}

// ---------------------------------------------------------------------------
// Pack V (post-quant) -> global TRANSPOSED bf16 hi/lo [bkv][64][S_PAD],
// zero-padded cols >= S_LEN. Block per (bkv, 64-key tile); LDS transpose.
// ---------------------------------------------------------------------------
__global__ __launch_bounds__(256)
void pack_v_kernel(const float* __restrict__ Vb,
                   ushort* __restrict__ VhiT, ushort* __restrict__ VloT) {
  __shared__ float T[64*LSTR];     // [key][d]
  const int tid = threadIdx.x;
  const int bkv = blockIdx.x / 33;
  const int kt  = blockIdx.x % 33;
  const int kbase = kt * 64;

  {  // coalesced read of 64x64 f32 tile
    const int key = tid >> 2, c16 = (tid & 3) * 16;
    const int s = kbase + key;
    if (s < S_LEN) {
      const float* src = Vb + ((size_t)bkv*S_LEN + s)*HD + c16;
      #pragma unroll
      for (int i=0;i<4;++i) {
        float4 v = *(const float4*)(src + 4*i);
        *(float4*)(T + key*LSTR + c16 + 4*i) = v;
      }
    } else {
      #pragma unroll
      for (int i=0;i<4;++i)
        *(float4*)(T + key*LSTR + c16 + 4*i) = make_float4(0.f,0.f,0.f,0.f);
    }
  }
  __syncthreads();
  {  // write transposed rows (d-major), 16 keys per thread
    const int d = tid >> 2, seg = tid & 3;
    ushort hb[16], lb[16];
    #pragma unroll
    for (int kk=0;kk<16;++kk) {
      float f = T[(seg*16 + kk)*LSTR + d];
      ushort h = f2bf(f);
      hb[kk] = h;
      lb[kk] = f2bf(f - bf2f(h));
    }
    uint uh[8], ul[8];
    #pragma unroll
    for (int m=0;m<8;++m) {
      uh[m] = (uint)hb[2*m] | ((uint)hb[2*m+1] << 16);
      ul[m] = (uint)lb[2*m] | ((uint)lb[2*m+1] << 16);
    }
    const size_t off = ((size_t)bkv*HD + d)*S_PAD + kbase + seg*16;
    *(uint4*)(VhiT + off)     = make_uint4(uh[0],uh[1],uh[2],uh[3]);
    *(uint4*)(VhiT + off + 8) = make_uint4(uh[4],uh[5],uh[6],uh[7]);
    *(uint4*)(VloT + off)     = make_uint4(ul[0],ul[1],ul[2],ul[3]);
    *(uint4*)(VloT + off + 8) = make_uint4(ul[4],ul[5],ul[6],ul[7]);
  }
}

// ---------------------------------------------------------------------------
// Flash attention via MFMA (16x16x32 bf16), causal, GQA 3:1.
//   QK^T: 3-term split (qhi*khi + qlo*khi + qhi*klo)  -> f32-class logits
//   PV:   3-term split (phi*vhi + phi*vlo + plo*vhi)  -> f32-class output
// Block: 4 waves; wave w owns q-rows [16w,16w+16) of a 64-row q-tile.
// Frag maps (m89-verified): A row=lane&15, k=8*(lane>>4)+e;
//                           B col=lane&15, k=8*(lane>>4)+e;
//                           D col=lane&15, row=4*(lane>>4)+reg.
// ---------------------------------------------------------------------------
__global__ __launch_bounds__(256)
void attn_kernel(const float* __restrict__ Q,
                 const ushort* __restrict__ KhiG, const ushort* __restrict__ KloG,
                 const ushort* __restrict__ VhiT, const ushort* __restrict__ VloT,
                 float* __restrict__ A) {
  __shared__ __align__(16) ushort Khi[64*KSTR];
  __shared__ __align__(16) ushort Klo[64*KSTR];
  __shared__ __align__(16) ushort Vhi[64*KSTR];
  __shared__ __align__(16) ushort Vlo[64*KSTR];
  __shared__ __align__(16) ushort Phi[64*KSTR];
  __shared__ __align__(16) ushort Plo[64*KSTR];

  const int tid  = threadIdx.x;
  const int wave = tid >> 6;
  const int lane = tid & 63;
  const int g    = lane >> 4;      // k-group / row-group
  const int c    = lane & 15;      // col (B/D) / row (A) lane index

  const int qt = (int)gridDim.x - 1 - (int)blockIdx.x;   // heavy tiles first
  const int bh = blockIdx.y;
  const int b = bh / NH, h = bh % NH, kvh = h / (NH/NKV);
  const int bkv = b*NKV + kvh;
  const float* Qg = Q + ((size_t)(b*NH + h)*S_LEN)*HD;
  const ushort* KhiB = KhiG + (size_t)bkv*S_PAD*HD;
  const ushort* KloB = KloG + (size_t)bkv*S_PAD*HD;
  const ushort* VhiB = VhiT + (size_t)bkv*HD*S_PAD;
  const ushort* VloB = VloT + (size_t)bkv*HD*S_PAD;
  const int qbase = qt * 64;

  // ---- Q fragments (hi+lo split), A row = c
  s16x8 qhi[2], qlo[2];
  {
    int qrow = qbase + 16*wave + c;
    if (qrow > S_LEN-1) qrow = S_LEN-1;
    #pragma unroll
    for (int kc = 0; kc < 2; ++kc) {
      const float* qp = Qg + (size_t)qrow*HD + kc*32 + g*8;
      float4 q0 = *(const float4*)(qp);
      float4 q1 = *(const float4*)(qp + 4);
      float qv[8] = {q0.x,q0.y,q0.z,q0.w,q1.x,q1.y,q1.z,q1.w};
      #pragma unroll
      for (int e=0;e<8;++e) {
        ushort hi = f2bf(qv[e]);
        ushort lo = f2bf(qv[e] - bf2f(hi));
        qhi[kc][e] = (short)hi;
        qlo[kc][e] = (short)lo;
      }
    }
  }

  f32x4 acc_o[4];
  #pragma unroll
  for (int n=0;n<4;++n) acc_o[n] = (f32x4){0.f,0.f,0.f,0.f};
  float m_i[4], l_i[4];
  #pragma unroll
  for (int r=0;r<4;++r) { m_i[r] = -INFINITY; l_i[r] = 0.f; }

  // staging assignment: thread t copies rows (t>>3) and (t>>3)+32, seg t&7
  const int srow = tid >> 3;
  const int sseg = (tid & 7) * 8;

  const int nkt = qt + 1;
  for (int kt = 0; kt < nkt; ++kt) {
    const int kbase = kt * 64;
    __syncthreads();   // all frag reads of prev tile done before restaging

    // ---- stage packed K (row-major) and V (d-major) tiles: pure copies
    #pragma unroll
    for (int it=0; it<2; ++it) {
      const int r = srow + 32*it;
      const size_t kg = ((size_t)(kbase + r))*HD + sseg;
      *(uint4*)&Khi[r*KSTR + sseg] = *(const uint4*)(KhiB + kg);
      *(uint4*)&Klo[r*KSTR + sseg] = *(const uint4*)(KloB + kg);
      const size_t vg = (size_t)r*S_PAD + kbase + sseg;
      *(uint4*)&Vhi[r*KSTR + sseg] = *(const uint4*)(VhiB + vg);
      *(uint4*)&Vlo[r*KSTR + sseg] = *(const uint4*)(VloB + vg);
    }
    __syncthreads();

    // ---- QK^T (split-3): sc[n] = 16x16 scores for keys [16n,16n+16)
    f32x4 sc[4];
    #pragma unroll
    for (int n=0;n<4;++n) sc[n] = (f32x4){0.f,0.f,0.f,0.f};
    #pragma unroll
    for (int kc=0; kc<2; ++kc) {
      #pragma unroll
      for (int n=0;n<4;++n) {
        const int key = 16*n + c;
        const int d   = kc*32 + g*8;
        s16x8 khf = *(const s16x8*)&Khi[key*KSTR + d];
        s16x8 klf = *(const s16x8*)&Klo[key*KSTR + d];
        sc[n] = __builtin_amdgcn_mfma_f32_16x16x32_bf16(qhi[kc], khf, sc[n], 0, 0, 0);
        sc[n] = __builtin_amdgcn_mfma_f32_16x16x32_bf16(qlo[kc], khf, sc[n], 0, 0, 0);
        sc[n] = __builtin_amdgcn_mfma_f32_16x16x32_bf16(qhi[kc], klf, sc[n], 0, 0, 0);
      }
    }

    // ---- online softmax. Lane holds rows 16w+4g+r, cols kbase+16n+c.
    const bool diag = (kt == qt);
    #pragma unroll
    for (int r=0;r<4;++r) {
      const int grow = qbase + 16*wave + 4*g + r;
      float s[4];
      #pragma unroll
      for (int n=0;n<4;++n) {
        float sv = sc[n][r] * 0.125f;
        if (diag && (kbase + 16*n + c > grow)) sv = -INFINITY;
        s[n] = sv;
      }
      float rm = fmaxf(fmaxf(s[0],s[1]), fmaxf(s[2],s[3]));
      rm = fmaxf(rm, __shfl_xor(rm, 1));
      rm = fmaxf(rm, __shfl_xor(rm, 2));
      rm = fmaxf(rm, __shfl_xor(rm, 4));
      rm = fmaxf(rm, __shfl_xor(rm, 8));
      const float mn = fmaxf(m_i[r], rm);
      const float al = __expf(m_i[r] - mn);   // exp(-inf)=0 on first tile
      float sum = 0.f;
      float pv4[4];
      #pragma unroll
      for (int n=0;n<4;++n) {
        float pv = __expf(s[n] - mn);
        pv4[n] = pv;
        sum += pv;
      }
      sum += __shfl_xor(sum, 1);
      sum += __shfl_xor(sum, 2);
      sum += __shfl_xor(sum, 4);
      sum += __shfl_xor(sum, 8);
      l_i[r] = l_i[r]*al + sum;
      m_i[r] = mn;
      #pragma unroll
      for (int n=0;n<4;++n) acc_o[n][r] *= al;
      // store P hi/lo (own wave's rows only; intra-wave LDS RAW is in-order)
      #pragma unroll
      for (int n=0;n<4;++n) {
        const int po = (16*wave + 4*g + r)*KSTR + 16*n + c;
        ushort ph = f2bf(pv4[n]);
        Phi[po] = ph;
        Plo[po] = f2bf(pv4[n] - bf2f(ph));
      }
    }

    // ---- PV (split-3): O[16x64] += P[16x64] * V[64x64]
    #pragma unroll
    for (int kc=0; kc<2; ++kc) {
      const int pd = kc*32 + g*8;
      s16x8 pfh = *(const s16x8*)&Phi[(16*wave + c)*KSTR + pd];
      s16x8 pfl = *(const s16x8*)&Plo[(16*wave + c)*KSTR + pd];
      #pragma unroll
      for (int n=0;n<4;++n) {
        s16x8 vfh = *(const s16x8*)&Vhi[(16*n + c)*KSTR + pd];
        s16x8 vfl = *(const s16x8*)&Vlo[(16*n + c)*KSTR + pd];
        acc_o[n] = __builtin_amdgcn_mfma_f32_16x16x32_bf16(pfh, vfh, acc_o[n], 0, 0, 0);
        acc_o[n] = __builtin_amdgcn_mfma_f32_16x16x32_bf16(pfh, vfl, acc_o[n], 0, 0, 0);
        acc_o[n] = __builtin_amdgcn_mfma_f32_16x16x32_bf16(pfl, vfh, acc_o[n], 0, 0, 0);
      }
    }
  }

  // ---- epilogue: divide by l, write A (b, s, h*64+d)
  #pragma unroll
  for (int r=0;r<4;++r) {
    const int grow = qbase + 16*wave + 4*g + r;
    if (grow < S_LEN) {
      const float inv = 1.0f / l_i[r];
      #pragma unroll
      for (int n=0;n<4;++n)
        A[((size_t)(b*S_LEN + grow))*EMB + h*HD + 16*n + c] = acc_o[n][r] * inv;
    }
  }
}

// ---------------------------------------------------------------------------
// Output projection via MFMA (split-bf16 3-term): out = A @ o_w^T
// M=4128, N=576, K=576. Block 64x64, 4 waves; wave w -> rows [16w,16w+16).
// Downstream of all quantization -> numerically safe to run in split-bf16.
// ---------------------------------------------------------------------------
__global__ __launch_bounds__(256)
void oproj_kernel(const float* __restrict__ A, const float* __restrict__ ow,
                  float* __restrict__ out) {
  __shared__ __align__(16) ushort Ahi[64*KSTR];
  __shared__ __align__(16) ushort Alo[64*KSTR];
  __shared__ __align__(16) ushort Whi[64*KSTR];
  __shared__ __align__(16) ushort Wlo[64*KSTR];

  const int tid  = threadIdx.x;
  const int wave = tid >> 6;
  const int lane = tid & 63;
  const int g    = lane >> 4;
  const int c    = lane & 15;

  const int m0 = blockIdx.x * 64;
  const int n0 = blockIdx.y * 64;

  // staging: thread t handles row t>>2 (0..63), 16-elem k-segment (t&3)*16
  const int srow = tid >> 2;
  const int sseg = (tid & 3) * 16;
  int am = m0 + srow; if (am > NTOK-1) am = NTOK-1;
  const float* arow = A  + (size_t)am * EMB;
  const float* wrow = ow + (size_t)(n0 + srow) * EMB;   // always in-bounds (N=576)

  f32x4 acc[4];
  #pragma unroll
  for (int n=0;n<4;++n) acc[n] = (f32x4){0.f,0.f,0.f,0.f};

  for (int kc0 = 0; kc0 < EMB; kc0 += 64) {
    __syncthreads();
    // stage A and W tiles as bf16 hi/lo
    {
      float av[16], wv[16];
      #pragma unroll
      for (int i=0;i<4;++i) {
        float4 a4 = *(const float4*)(arow + kc0 + sseg + 4*i);
        float4 w4 = *(const float4*)(wrow + kc0 + sseg + 4*i);
        av[4*i+0]=a4.x; av[4*i+1]=a4.y; av[4*i+2]=a4.z; av[4*i+3]=a4.w;
        wv[4*i+0]=w4.x; wv[4*i+1]=w4.y; wv[4*i+2]=w4.z; wv[4*i+3]=w4.w;
      }
      uint ah[8], al[8], wh[8], wl[8];
      #pragma unroll
      for (int m=0;m<8;++m) {
        ushort h0 = f2bf(av[2*m]),   h1 = f2bf(av[2*m+1]);
        ushort l0 = f2bf(av[2*m]   - bf2f(h0));
        ushort l1 = f2bf(av[2*m+1] - bf2f(h1));
        ah[m] = (uint)h0 | ((uint)h1 << 16);
        al[m] = (uint)l0 | ((uint)l1 << 16);
        ushort g0 = f2bf(wv[2*m]),   g1 = f2bf(wv[2*m+1]);
        ushort m0_ = f2bf(wv[2*m]   - bf2f(g0));
        ushort m1_ = f2bf(wv[2*m+1] - bf2f(g1));
        wh[m] = (uint)g0 | ((uint)g1 << 16);
        wl[m] = (uint)m0_ | ((uint)m1_ << 16);
      }
      const int lo = srow*KSTR + sseg;
      *(uint4*)&Ahi[lo]     = make_uint4(ah[0],ah[1],ah[2],ah[3]);
      *(uint4*)&Ahi[lo + 8] = make_uint4(ah[4],ah[5],ah[6],ah[7]);
      *(uint4*)&Alo[lo]     = make_uint4(al[0],al[1],al[2],al[3]);
      *(uint4*)&Alo[lo + 8] = make_uint4(al[4],al[5],al[6],al[7]);
      *(uint4*)&Whi[lo]     = make_uint4(wh[0],wh[1],wh[2],wh[3]);
      *(uint4*)&Whi[lo + 8] = make_uint4(wh[4],wh[5],wh[6],wh[7]);
      *(uint4*)&Wlo[lo]     = make_uint4(wl[0],wl[1],wl[2],wl[3]);
      *(uint4*)&Wlo[lo + 8] = make_uint4(wl[4],wl[5],wl[6],wl[7]);
    }
    __syncthreads();

    #pragma unroll
    for (int kc=0; kc<2; ++kc) {
      const int d = kc*32 + g*8;
      s16x8 a_h = *(const s16x8*)&Ahi[(16*wave + c)*KSTR + d];
      s16x8 a_l = *(const s16x8*)&Alo[(16*wave + c)*KSTR + d];
      #pragma unroll
      for (int n=0;n<4;++n) {
        s16x8 w_h = *(const s16x8*)&Whi[(16*n + c)*KSTR + d];
        s16x8 w_l = *(const s16x8*)&Wlo[(16*n + c)*KSTR + d];
        acc[n] = __builtin_amdgcn_mfma_f32_16x16x32_bf16(a_h, w_h, acc[n], 0, 0, 0);
        acc[n] = __builtin_amdgcn_mfma_f32_16x16x32_bf16(a_l, w_h, acc[n], 0, 0, 0);
        acc[n] = __builtin_amdgcn_mfma_f32_16x16x32_bf16(a_h, w_l, acc[n], 0, 0, 0);
      }
    }
  }

  // epilogue: D row = 16w+4g+r, col = 16n+c
  #pragma unroll
  for (int r=0;r<4;++r) {
    const int m = m0 + 16*wave + 4*g + r;
    if (m < NTOK) {
      #pragma unroll
      for (int n=0;n<4;++n)
        out[(size_t)m*EMB + n0 + 16*n + c] = acc[n][r];
    }
  }
}

// ---------------------------------------------------------------------------
extern "C" void kernel_launch(void* const* d_in, const int* in_sizes, int n_in,
                              void* d_out, int out_size, void* d_ws, size_t ws_size,
                              hipStream_t stream) {
  const float* x   = (const float*)d_in[0];
  const float* qw  = (const float*)d_in[1];
  const float* kw  = (const float*)d_in[2];
  const float* vw  = (const float*)d_in[3];
  const float* qrw = (const float*)d_in[4];
  const float* krw = (const float*)d_in[5];
  const float* ow  = (const float*)d_in[6];
  float* out = (float*)d_out;

  float* ws = (float*)d_ws;
  float* Qb = ws;
  float* Kb = Qb + QSZ;
  float* Vb = Kb + KSZ;
  float* Ab = Vb + VSZ;
  ushort* KhiG = (ushort*)(Ab + ASZ);
  ushort* KloG = KhiG + KPK;
  ushort* VhiT = KloG + KPK;
  ushort* VloT = VhiT + KPK;

  // 1. fused projections
  dim3 g1((NTOK + 63)/64, 960/64);            // 65 x 15
  proj_kernel<<<g1, 256, 0, stream>>>(x, qw, kw, vw, qrw, krw, Qb, Kb, Vb);

  // 2. rope on q_r / k_r
  {
    int total = NB*(NH+NKV)*S_LEN;
    rope_kernel<<<(total+255)/256, 256, 0, stream>>>(Qb, Kb);
  }

  // 3. fake-quant K (first 2048) and V (first 2032)
  {
    int kwaves = NB*NKV*32;
    quant_key_kernel<<<(kwaves*64+255)/256, 256, 0, stream>>>(Kb);
    int vwaves = NB*NKV*2032;
    quant_value_kernel<<<(vwaves*64+255)/256, 256, 0, stream>>>(Vb);
  }

  // 4. pack KV to bf16 hi/lo (K row-major, V transposed), zero-padded
  {
    int ksegs = NB*NKV*S_PAD*8;
    pack_k_kernel<<<(ksegs+255)/256, 256, 0, stream>>>(Kb, KhiG, KloG);
    pack_v_kernel<<<NB*NKV*33, 256, 0, stream>>>(Vb, VhiT, VloT);
  }

  // 5. causal flash attention (MFMA, split-bf16)
  dim3 ga((S_LEN+63)/64, NB*NH);               // 33 x 18
  attn_kernel<<<ga, 256, 0, stream>>>(Qb, KhiG, KloG, VhiT, VloT, Ab);

  // 6. output projection (MFMA, split-bf16)
  dim3 go((NTOK + 63)/64, EMB/64);             // 65 x 9
  oproj_kernel<<<go, 256, 0, stream>>>(Ab, ow, out);
}

// Round 8
// 260.364 us; speedup vs baseline: 2.0279x; 1.2099x over previous
//
#include <hip/hip_runtime.h>
#include <math.h>

#define S_LEN 2064
#define S_PAD 2112               // 33 tiles * 64, zero-padded packed KV
#define NB 2
#define NH 9
#define NKV 3
#define HD 64
#define EMB 576
#define NTOK (NB*S_LEN)          // 4128
#define LSTR 68                  // padded f32 LDS stride
#define KSTR 72                  // bf16 LDS stride: 144B rows -> bank-balanced b128 reads

#define QSZ (NB*NH*S_LEN*HD)     // 2377728
#define KSZ (NB*NKV*S_LEN*HD)    // 792576
#define VSZ (NB*NKV*S_LEN*HD)    // 792576
#define ASZ (NB*S_LEN*EMB)       // 2377728
#define KPK (NB*NKV*S_PAD*HD)    // 811008 (per packed buffer, ushorts)

typedef float  f32x4  __attribute__((ext_vector_type(4)));
typedef short  s16x8  __attribute__((ext_vector_type(8)));

// f32 <-> bf16 (RNE), bit-level
static __device__ __forceinline__ ushort f2bf(float x) {
  union { float f; unsigned u; } a; a.f = x;
  unsigned r = a.u + 0x7fffu + ((a.u >> 16) & 1u);
  return (ushort)(r >> 16);
}
static __device__ __forceinline__ float bf2f(ushort h) {
  union { unsigned u; float f; } a; a.u = ((unsigned)h) << 16;
  return a.f;
}

// ---------------------------------------------------------------------------
// Fused QKV/Qr/Kr projection via MFMA, split-4 bf16:
//   y = xhi*whi + xlo*whi + xhi*wlo + xlo*wlo  (f32-reorder-class accuracy,
//   same error class as the previous f32 SGEMM vs the JAX reference).
// Block 64x64, 4 waves; wave w -> rows [16w,16w+16). Scatter epilogue.
// ---------------------------------------------------------------------------
__global__ __launch_bounds__(256)
void proj_kernel(const float* __restrict__ x,
                 const float* __restrict__ qw, const float* __restrict__ kw,
                 const float* __restrict__ vw, const float* __restrict__ qrw,
                 const float* __restrict__ krw,
                 float* __restrict__ Qb, float* __restrict__ Kb,
                 float* __restrict__ Vb) {
  __shared__ __align__(16) ushort Xhi[64*KSTR];
  __shared__ __align__(16) ushort Xlo[64*KSTR];
  __shared__ __align__(16) ushort Whi[64*KSTR];
  __shared__ __align__(16) ushort Wlo[64*KSTR];

  const int tid  = threadIdx.x;
  const int wave = tid >> 6;
  const int lane = tid & 63;
  const int g    = lane >> 4;
  const int c    = lane & 15;

  const int m0 = blockIdx.x * 64;
  const int n0 = blockIdx.y * 64;

  // staging: thread t -> row t>>2 (0..63), 16-elem k-segment (t&3)*16
  const int srow = tid >> 2;
  const int sseg = (tid & 3) * 16;
  int gm = m0 + srow; if (gm > NTOK-1) gm = NTOK-1;
  const float* xrow = x + (size_t)gm * EMB;
  const int col = n0 + srow;
  const float* wrow;
  if (col < 504)      wrow = qw  + (size_t)col       * EMB;
  else if (col < 672) wrow = kw  + (size_t)(col-504) * EMB;
  else if (col < 864) wrow = vw  + (size_t)(col-672) * EMB;
  else if (col < 936) wrow = qrw + (size_t)(col-864) * EMB;
  else                wrow = krw + (size_t)(col-936) * EMB;

  f32x4 acc[4];
  #pragma unroll
  for (int n=0;n<4;++n) acc[n] = (f32x4){0.f,0.f,0.f,0.f};

  for (int kc0 = 0; kc0 < EMB; kc0 += 64) {
    __syncthreads();
    {
      float xv[16], wv[16];
      #pragma unroll
      for (int i=0;i<4;++i) {
        float4 x4 = *(const float4*)(xrow + kc0 + sseg + 4*i);
        float4 w4 = *(const float4*)(wrow + kc0 + sseg + 4*i);
        xv[4*i+0]=x4.x; xv[4*i+1]=x4.y; xv[4*i+2]=x4.z; xv[4*i+3]=x4.w;
        wv[4*i+0]=w4.x; wv[4*i+1]=w4.y; wv[4*i+2]=w4.z; wv[4*i+3]=w4.w;
      }
      uint xh[8], xl[8], wh[8], wl[8];
      #pragma unroll
      for (int m=0;m<8;++m) {
        ushort h0 = f2bf(xv[2*m]),   h1 = f2bf(xv[2*m+1]);
        ushort l0 = f2bf(xv[2*m]   - bf2f(h0));
        ushort l1 = f2bf(xv[2*m+1] - bf2f(h1));
        xh[m] = (uint)h0 | ((uint)h1 << 16);
        xl[m] = (uint)l0 | ((uint)l1 << 16);
        ushort g0 = f2bf(wv[2*m]),   g1 = f2bf(wv[2*m+1]);
        ushort k0 = f2bf(wv[2*m]   - bf2f(g0));
        ushort k1 = f2bf(wv[2*m+1] - bf2f(g1));
        wh[m] = (uint)g0 | ((uint)g1 << 16);
        wl[m] = (uint)k0 | ((uint)k1 << 16);
      }
      const int lo = srow*KSTR + sseg;
      *(uint4*)&Xhi[lo]     = make_uint4(xh[0],xh[1],xh[2],xh[3]);
      *(uint4*)&Xhi[lo + 8] = make_uint4(xh[4],xh[5],xh[6],xh[7]);
      *(uint4*)&Xlo[lo]     = make_uint4(xl[0],xl[1],xl[2],xl[3]);
      *(uint4*)&Xlo[lo + 8] = make_uint4(xl[4],xl[5],xl[6],xl[7]);
      *(uint4*)&Whi[lo]     = make_uint4(wh[0],wh[1],wh[2],wh[3]);
      *(uint4*)&Whi[lo + 8] = make_uint4(wh[4],wh[5],wh[6],wh[7]);
      *(uint4*)&Wlo[lo]     = make_uint4(wl[0],wl[1],wl[2],wl[3]);
      *(uint4*)&Wlo[lo + 8] = make_uint4(wl[4],wl[5],wl[6],wl[7]);
    }
    __syncthreads();

    #pragma unroll
    for (int kc=0; kc<2; ++kc) {
      const int d = kc*32 + g*8;
      s16x8 x_h = *(const s16x8*)&Xhi[(16*wave + c)*KSTR + d];
      s16x8 x_l = *(const s16x8*)&Xlo[(16*wave + c)*KSTR + d];
      #pragma unroll
      for (int n=0;n<4;++n) {
        s16x8 w_h = *(const s16x8*)&Whi[(16*n + c)*KSTR + d];
        s16x8 w_l = *(const s16x8*)&Wlo[(16*n + c)*KSTR + d];
        acc[n] = __builtin_amdgcn_mfma_f32_16x16x32_bf16(x_h, w_h, acc[n], 0, 0, 0);
        acc[n] = __builtin_amdgcn_mfma_f32_16x16x32_bf16(x_l, w_h, acc[n], 0, 0, 0);
        acc[n] = __builtin_amdgcn_mfma_f32_16x16x32_bf16(x_h, w_l, acc[n], 0, 0, 0);
        acc[n] = __builtin_amdgcn_mfma_f32_16x16x32_bf16(x_l, w_l, acc[n], 0, 0, 0);
      }
    }
  }

  // epilogue: D row = m0+16w+4g+r, col = n0+16n+c; scatter into Q/K/V
  #pragma unroll
  for (int r=0;r<4;++r) {
    const int row = m0 + 16*wave + 4*g + r;
    if (row >= NTOK) continue;
    const int b = row / S_LEN, s = row % S_LEN;
    #pragma unroll
    for (int n=0;n<4;++n) {
      const int cc = n0 + 16*n + c;
      const float v = acc[n][r];
      if (cc < 504) {
        int h = cc / 56, d = cc % 56;
        Qb[(((size_t)(b*NH+h))*S_LEN + s)*HD + d] = v;
      } else if (cc < 672) {
        int h = (cc-504)/56, d = (cc-504)%56;
        Kb[(((size_t)(b*NKV+h))*S_LEN + s)*HD + d] = v;
      } else if (cc < 864) {
        int h = (cc-672)/64, d = (cc-672)%64;
        Vb[(((size_t)(b*NKV+h))*S_LEN + s)*HD + d] = v;
      } else if (cc < 936) {
        int h = (cc-864)/8, d = 56 + (cc-864)%8;
        Qb[(((size_t)(b*NH+h))*S_LEN + s)*HD + d] = v;
      } else {
        int h = (cc-936)/8, d = 56 + (cc-936)%8;
        Kb[(((size_t)(b*NKV+h))*S_LEN + s)*HD + d] = v;
      }
    }
  }
}

// ---------------------------------------------------------------------------
// In-place partial RoPE on dims 56..63 of Q (9 heads) and K (3 heads).
// ---------------------------------------------------------------------------
__global__ void rope_kernel(float* __restrict__ Qb, float* __restrict__ Kb) {
  const int idx = blockIdx.x * blockDim.x + threadIdx.x;
  const int total = NB*(NH+NKV)*S_LEN;
  if (idx >= total) return;
  const int s  = idx % S_LEN;
  const int bh = idx / S_LEN;
  const int b  = bh / (NH+NKV), hh = bh % (NH+NKV);
  float* base;
  if (hh < NH) base = Qb + (((size_t)(b*NH + hh))*S_LEN + s)*HD + 56;
  else         base = Kb + (((size_t)(b*NKV + (hh-NH)))*S_LEN + s)*HD + 56;

  float4 a = *(const float4*)(base);
  float4 c = *(const float4*)(base + 4);
  float xv[8] = {a.x,a.y,a.z,a.w,c.x,c.y,c.z,c.w};
  const float es[4] = {0.0f, 2.0f/64.0f, 32.0f/64.0f, 34.0f/64.0f};
  const float ps = (float)s;
  float o[8];
  #pragma unroll
  for (int j=0;j<4;++j) {
    float th  = 1.0f / powf(100000.0f, es[j]);
    float ang = ps * th;
    float cs = cosf(ang), sn = sinf(ang);
    o[j]   = xv[j]*cs   - xv[j+4]*sn;
    o[j+4] = xv[j+4]*cs + xv[j]*sn;
  }
  *(float4*)(base)     = make_float4(o[0],o[1],o[2],o[3]);
  *(float4*)(base + 4) = make_float4(o[4],o[5],o[6],o[7]);
}

// ---------------------------------------------------------------------------
// 2-bit fake-quant of K (per 64-token group per dim, first 2048 tokens)
// ---------------------------------------------------------------------------
__global__ void quant_key_kernel(float* __restrict__ Kb) {
  const int wid  = (blockIdx.x * blockDim.x + threadIdx.x) >> 6;
  const int lane = threadIdx.x & 63;
  if (wid >= NB*NKV*32) return;
  const int bkh = wid >> 5, sg = wid & 31;
  float* base = Kb + ((size_t)bkh*S_LEN + sg*64)*HD + lane;
  float vals[64];
  float mn = 1e30f, mx = -1e30f;
  #pragma unroll
  for (int s=0;s<64;++s) {
    float v = fminf(fmaxf(base[s*HD], -10000.0f), 10000.0f);
    vals[s] = v;
    mn = fminf(mn, v); mx = fmaxf(mx, v);
  }
  float scale = (mx - mn) / 3.0f;
  if (scale == 0.0f) scale = 1.0f;
  #pragma unroll
  for (int s=0;s<64;++s) {
    float q = rintf((vals[s] - mn) / scale);
    base[s*HD] = q * scale + mn;
  }
}

// ---------------------------------------------------------------------------
// 2-bit fake-quant of V (per token over d=64, first 2032 tokens)
// ---------------------------------------------------------------------------
__global__ void quant_value_kernel(float* __restrict__ Vb) {
  const int wid  = (blockIdx.x * blockDim.x + threadIdx.x) >> 6;
  const int lane = threadIdx.x & 63;
  const int total = NB*NKV*2032;
  if (wid >= total) return;
  const int bkh = wid / 2032, s = wid % 2032;
  float* p = Vb + ((size_t)bkh*S_LEN + s)*HD + lane;
  float v = fminf(fmaxf(*p, -10000.0f), 10000.0f);
  float mn = v, mx = v;
  #pragma unroll
  for (int m=1;m<64;m<<=1) {
    mn = fminf(mn, __shfl_xor(mn, m));
    mx = fmaxf(mx, __shfl_xor(mx, m));
  }
  float scale = (mx - mn) / 3.0f;
  if (scale == 0.0f) scale = 1.0f;
  float q = rintf((v - mn) / scale);
  *p = q * scale + mn;
}

// ---------------------------------------------------------------------------
// Pack K (post-rope, post-quant) -> global bf16 hi/lo [bkv][S_PAD][64]
// ---------------------------------------------------------------------------
__global__ __launch_bounds__(256)
void pack_k_kernel(const float* __restrict__ Kb,
                   ushort* __restrict__ KhiG, ushort* __restrict__ KloG) {
  const int idx = blockIdx.x * blockDim.x + threadIdx.x;
  const int total = NB*NKV*S_PAD*8;
  if (idx >= total) return;
  const int bkv = idx / (S_PAD*8);
  const int rem = idx % (S_PAD*8);
  const int s = rem >> 3, d0 = (rem & 7) * 8;
  uint u_h[4], u_l[4];
  if (s < S_LEN) {
    const float* src = Kb + ((size_t)bkv*S_LEN + s)*HD + d0;
    float4 a = *(const float4*)(src);
    float4 b = *(const float4*)(src + 4);
    float v[8] = {a.x,a.y,a.z,a.w,b.x,b.y,b.z,b.w};
    ushort hb[8], lb[8];
    #pragma unroll
    for (int e=0;e<8;++e) {
      hb[e] = f2bf(v[e]);
      lb[e] = f2bf(v[e] - bf2f(hb[e]));
    }
    #pragma unroll
    for (int m=0;m<4;++m) {
      u_h[m] = (uint)hb[2*m] | ((uint)hb[2*m+1] << 16);
      u_l[m] = (uint)lb[2*m] | ((uint)lb[2*m+1] << 16);
    }
  } else {
    #pragma unroll
    for (int m=0;m<4;++m) { u_h[m] = 0; u_l[m] = 0; }
  }
  const size_t off = ((size_t)bkv*S_PAD + s)*HD + d0;
  *(uint4*)(KhiG + off) = make_uint4(u_h[0],u_h[1],u_h[2],u_h[3]);
  *(uint4*)(KloG + off) = make_uint4(u_l[0],u_l[1],u_l[2],u_l[3]);
}

// ---------------------------------------------------------------------------
// Pack V (post-quant) -> global TRANSPOSED bf16 (hi only) [bkv][64][S_PAD]
// ---------------------------------------------------------------------------
__global__ __launch_bounds__(256)
void pack_v_kernel(const float* __restrict__ Vb,
                   ushort* __restrict__ VhiT) {
  __shared__ float T[64*LSTR];     // [key][d]
  const int tid = threadIdx.x;
  const int bkv = blockIdx.x / 33;
  const int kt  = blockIdx.x % 33;
  const int kbase = kt * 64;

  {  // coalesced read of 64x64 f32 tile
    const int key = tid >> 2, c16 = (tid & 3) * 16;
    const int s = kbase + key;
    if (s < S_LEN) {
      const float* src = Vb + ((size_t)bkv*S_LEN + s)*HD + c16;
      #pragma unroll
      for (int i=0;i<4;++i) {
        float4 v = *(const float4*)(src + 4*i);
        *(float4*)(T + key*LSTR + c16 + 4*i) = v;
      }
    } else {
      #pragma unroll
      for (int i=0;i<4;++i)
        *(float4*)(T + key*LSTR + c16 + 4*i) = make_float4(0.f,0.f,0.f,0.f);
    }
  }
  __syncthreads();
  {  // write transposed rows (d-major), 16 keys per thread
    const int d = tid >> 2, seg = tid & 3;
    ushort hb[16];
    #pragma unroll
    for (int kk=0;kk<16;++kk)
      hb[kk] = f2bf(T[(seg*16 + kk)*LSTR + d]);
    uint uh[8];
    #pragma unroll
    for (int m=0;m<8;++m)
      uh[m] = (uint)hb[2*m] | ((uint)hb[2*m+1] << 16);
    const size_t off = ((size_t)bkv*HD + d)*S_PAD + kbase + seg*16;
    *(uint4*)(VhiT + off)     = make_uint4(uh[0],uh[1],uh[2],uh[3]);
    *(uint4*)(VhiT + off + 8) = make_uint4(uh[4],uh[5],uh[6],uh[7]);
  }
}

// ---------------------------------------------------------------------------
// Flash attention via MFMA (16x16x32 bf16), causal, GQA 3:1.
//   QK^T: 3-term split (f32-class logits — exp amplifies logit error)
//   PV:   plain bf16 (P in [0,1], near-uniform attention -> ~1e-4-class out)
// LDS: Khi, Klo, Vhi, Phi = 36.9 KB -> 4 blocks/CU (was 54 KB -> 2).
// ---------------------------------------------------------------------------
__global__ __launch_bounds__(256)
void attn_kernel(const float* __restrict__ Q,
                 const ushort* __restrict__ KhiG, const ushort* __restrict__ KloG,
                 const ushort* __restrict__ VhiT,
                 float* __restrict__ A) {
  __shared__ __align__(16) ushort Khi[64*KSTR];
  __shared__ __align__(16) ushort Klo[64*KSTR];
  __shared__ __align__(16) ushort Vhi[64*KSTR];
  __shared__ __align__(16) ushort Phi[64*KSTR];

  const int tid  = threadIdx.x;
  const int wave = tid >> 6;
  const int lane = tid & 63;
  const int g    = lane >> 4;      // k-group / row-group
  const int c    = lane & 15;      // col (B/D) / row (A) lane index

  const int qt = (int)gridDim.x - 1 - (int)blockIdx.x;   // heavy tiles first
  const int bh = blockIdx.y;
  const int b = bh / NH, h = bh % NH, kvh = h / (NH/NKV);
  const int bkv = b*NKV + kvh;
  const float* Qg = Q + ((size_t)(b*NH + h)*S_LEN)*HD;
  const ushort* KhiB = KhiG + (size_t)bkv*S_PAD*HD;
  const ushort* KloB = KloG + (size_t)bkv*S_PAD*HD;
  const ushort* VhiB = VhiT + (size_t)bkv*HD*S_PAD;
  const int qbase = qt * 64;

  // ---- Q fragments (hi+lo split), A row = c
  s16x8 qhi[2], qlo[2];
  {
    int qrow = qbase + 16*wave + c;
    if (qrow > S_LEN-1) qrow = S_LEN-1;
    #pragma unroll
    for (int kc = 0; kc < 2; ++kc) {
      const float* qp = Qg + (size_t)qrow*HD + kc*32 + g*8;
      float4 q0 = *(const float4*)(qp);
      float4 q1 = *(const float4*)(qp + 4);
      float qv[8] = {q0.x,q0.y,q0.z,q0.w,q1.x,q1.y,q1.z,q1.w};
      #pragma unroll
      for (int e=0;e<8;++e) {
        ushort hi = f2bf(qv[e]);
        ushort lo = f2bf(qv[e] - bf2f(hi));
        qhi[kc][e] = (short)hi;
        qlo[kc][e] = (short)lo;
      }
    }
  }

  f32x4 acc_o[4];
  #pragma unroll
  for (int n=0;n<4;++n) acc_o[n] = (f32x4){0.f,0.f,0.f,0.f};
  float m_i[4], l_i[4];
  #pragma unroll
  for (int r=0;r<4;++r) { m_i[r] = -INFINITY; l_i[r] = 0.f; }

  // staging assignment: thread t copies rows (t>>3) and (t>>3)+32, seg t&7
  const int srow = tid >> 3;
  const int sseg = (tid & 7) * 8;

  const int nkt = qt + 1;
  for (int kt = 0; kt < nkt; ++kt) {
    const int kbase = kt * 64;
    __syncthreads();   // all frag reads of prev tile done before restaging

    // ---- stage packed K (row-major) and V (d-major) tiles: pure copies
    #pragma unroll
    for (int it=0; it<2; ++it) {
      const int r = srow + 32*it;
      const size_t kg = ((size_t)(kbase + r))*HD + sseg;
      *(uint4*)&Khi[r*KSTR + sseg] = *(const uint4*)(KhiB + kg);
      *(uint4*)&Klo[r*KSTR + sseg] = *(const uint4*)(KloB + kg);
      const size_t vg = (size_t)r*S_PAD + kbase + sseg;
      *(uint4*)&Vhi[r*KSTR + sseg] = *(const uint4*)(VhiB + vg);
    }
    __syncthreads();

    // ---- QK^T (split-3): sc[n] = 16x16 scores for keys [16n,16n+16)
    f32x4 sc[4];
    #pragma unroll
    for (int n=0;n<4;++n) sc[n] = (f32x4){0.f,0.f,0.f,0.f};
    #pragma unroll
    for (int kc=0; kc<2; ++kc) {
      #pragma unroll
      for (int n=0;n<4;++n) {
        const int key = 16*n + c;
        const int d   = kc*32 + g*8;
        s16x8 khf = *(const s16x8*)&Khi[key*KSTR + d];
        s16x8 klf = *(const s16x8*)&Klo[key*KSTR + d];
        sc[n] = __builtin_amdgcn_mfma_f32_16x16x32_bf16(qhi[kc], khf, sc[n], 0, 0, 0);
        sc[n] = __builtin_amdgcn_mfma_f32_16x16x32_bf16(qlo[kc], khf, sc[n], 0, 0, 0);
        sc[n] = __builtin_amdgcn_mfma_f32_16x16x32_bf16(qhi[kc], klf, sc[n], 0, 0, 0);
      }
    }

    // ---- online softmax. Lane holds rows 16w+4g+r, cols kbase+16n+c.
    const bool diag = (kt == qt);
    #pragma unroll
    for (int r=0;r<4;++r) {
      const int grow = qbase + 16*wave + 4*g + r;
      float s[4];
      #pragma unroll
      for (int n=0;n<4;++n) {
        float sv = sc[n][r] * 0.125f;
        if (diag && (kbase + 16*n + c > grow)) sv = -INFINITY;
        s[n] = sv;
      }
      float rm = fmaxf(fmaxf(s[0],s[1]), fmaxf(s[2],s[3]));
      rm = fmaxf(rm, __shfl_xor(rm, 1));
      rm = fmaxf(rm, __shfl_xor(rm, 2));
      rm = fmaxf(rm, __shfl_xor(rm, 4));
      rm = fmaxf(rm, __shfl_xor(rm, 8));
      const float mn = fmaxf(m_i[r], rm);
      const float al = __expf(m_i[r] - mn);   // exp(-inf)=0 on first tile
      float sum = 0.f;
      float pv4[4];
      #pragma unroll
      for (int n=0;n<4;++n) {
        float pv = __expf(s[n] - mn);
        pv4[n] = pv;
        sum += pv;
      }
      sum += __shfl_xor(sum, 1);
      sum += __shfl_xor(sum, 2);
      sum += __shfl_xor(sum, 4);
      sum += __shfl_xor(sum, 8);
      l_i[r] = l_i[r]*al + sum;
      m_i[r] = mn;
      #pragma unroll
      for (int n=0;n<4;++n) acc_o[n][r] *= al;
      // store P bf16 (own wave's rows only; intra-wave LDS RAW is in-order)
      #pragma unroll
      for (int n=0;n<4;++n)
        Phi[(16*wave + 4*g + r)*KSTR + 16*n + c] = f2bf(pv4[n]);
    }

    // ---- PV (plain bf16): O[16x64] += P[16x64] * V[64x64]
    #pragma unroll
    for (int kc=0; kc<2; ++kc) {
      const int pd = kc*32 + g*8;
      s16x8 pfh = *(const s16x8*)&Phi[(16*wave + c)*KSTR + pd];
      #pragma unroll
      for (int n=0;n<4;++n) {
        s16x8 vfh = *(const s16x8*)&Vhi[(16*n + c)*KSTR + pd];
        acc_o[n] = __builtin_amdgcn_mfma_f32_16x16x32_bf16(pfh, vfh, acc_o[n], 0, 0, 0);
      }
    }
  }

  // ---- epilogue: divide by l, write A (b, s, h*64+d)
  #pragma unroll
  for (int r=0;r<4;++r) {
    const int grow = qbase + 16*wave + 4*g + r;
    if (grow < S_LEN) {
      const float inv = 1.0f / l_i[r];
      #pragma unroll
      for (int n=0;n<4;++n)
        A[((size_t)(b*S_LEN + grow))*EMB + h*HD + 16*n + c] = acc_o[n][r] * inv;
    }
  }
}

// ---------------------------------------------------------------------------
// Output projection via MFMA (split-bf16 3-term): out = A @ o_w^T
// ---------------------------------------------------------------------------
__global__ __launch_bounds__(256)
void oproj_kernel(const float* __restrict__ A, const float* __restrict__ ow,
                  float* __restrict__ out) {
  __shared__ __align__(16) ushort Ahi[64*KSTR];
  __shared__ __align__(16) ushort Alo[64*KSTR];
  __shared__ __align__(16) ushort Whi[64*KSTR];
  __shared__ __align__(16) ushort Wlo[64*KSTR];

  const int tid  = threadIdx.x;
  const int wave = tid >> 6;
  const int lane = tid & 63;
  const int g    = lane >> 4;
  const int c    = lane & 15;

  const int m0 = blockIdx.x * 64;
  const int n0 = blockIdx.y * 64;

  const int srow = tid >> 2;
  const int sseg = (tid & 3) * 16;
  int am = m0 + srow; if (am > NTOK-1) am = NTOK-1;
  const float* arow = A  + (size_t)am * EMB;
  const float* wrow = ow + (size_t)(n0 + srow) * EMB;   // always in-bounds (N=576)

  f32x4 acc[4];
  #pragma unroll
  for (int n=0;n<4;++n) acc[n] = (f32x4){0.f,0.f,0.f,0.f};

  for (int kc0 = 0; kc0 < EMB; kc0 += 64) {
    __syncthreads();
    {
      float av[16], wv[16];
      #pragma unroll
      for (int i=0;i<4;++i) {
        float4 a4 = *(const float4*)(arow + kc0 + sseg + 4*i);
        float4 w4 = *(const float4*)(wrow + kc0 + sseg + 4*i);
        av[4*i+0]=a4.x; av[4*i+1]=a4.y; av[4*i+2]=a4.z; av[4*i+3]=a4.w;
        wv[4*i+0]=w4.x; wv[4*i+1]=w4.y; wv[4*i+2]=w4.z; wv[4*i+3]=w4.w;
      }
      uint ah[8], al[8], wh[8], wl[8];
      #pragma unroll
      for (int m=0;m<8;++m) {
        ushort h0 = f2bf(av[2*m]),   h1 = f2bf(av[2*m+1]);
        ushort l0 = f2bf(av[2*m]   - bf2f(h0));
        ushort l1 = f2bf(av[2*m+1] - bf2f(h1));
        ah[m] = (uint)h0 | ((uint)h1 << 16);
        al[m] = (uint)l0 | ((uint)l1 << 16);
        ushort g0 = f2bf(wv[2*m]),   g1 = f2bf(wv[2*m+1]);
        ushort m0_ = f2bf(wv[2*m]   - bf2f(g0));
        ushort m1_ = f2bf(wv[2*m+1] - bf2f(g1));
        wh[m] = (uint)g0 | ((uint)g1 << 16);
        wl[m] = (uint)m0_ | ((uint)m1_ << 16);
      }
      const int lo = srow*KSTR + sseg;
      *(uint4*)&Ahi[lo]     = make_uint4(ah[0],ah[1],ah[2],ah[3]);
      *(uint4*)&Ahi[lo + 8] = make_uint4(ah[4],ah[5],ah[6],ah[7]);
      *(uint4*)&Alo[lo]     = make_uint4(al[0],al[1],al[2],al[3]);
      *(uint4*)&Alo[lo + 8] = make_uint4(al[4],al[5],al[6],al[7]);
      *(uint4*)&Whi[lo]     = make_uint4(wh[0],wh[1],wh[2],wh[3]);
      *(uint4*)&Whi[lo + 8] = make_uint4(wh[4],wh[5],wh[6],wh[7]);
      *(uint4*)&Wlo[lo]     = make_uint4(wl[0],wl[1],wl[2],wl[3]);
      *(uint4*)&Wlo[lo + 8] = make_uint4(wl[4],wl[5],wl[6],wl[7]);
    }
    __syncthreads();

    #pragma unroll
    for (int kc=0; kc<2; ++kc) {
      const int d = kc*32 + g*8;
      s16x8 a_h = *(const s16x8*)&Ahi[(16*wave + c)*KSTR + d];
      s16x8 a_l = *(const s16x8*)&Alo[(16*wave + c)*KSTR + d];
      #pragma unroll
      for (int n=0;n<4;++n) {
        s16x8 w_h = *(const s16x8*)&Whi[(16*n + c)*KSTR + d];
        s16x8 w_l = *(const s16x8*)&Wlo[(16*n + c)*KSTR + d];
        acc[n] = __builtin_amdgcn_mfma_f32_16x16x32_bf16(a_h, w_h, acc[n], 0, 0, 0);
        acc[n] = __builtin_amdgcn_mfma_f32_16x16x32_bf16(a_l, w_h, acc[n], 0, 0, 0);
        acc[n] = __builtin_amdgcn_mfma_f32_16x16x32_bf16(a_h, w_l, acc[n], 0, 0, 0);
      }
    }
  }

  #pragma unroll
  for (int r=0;r<4;++r) {
    const int m = m0 + 16*wave + 4*g + r;
    if (m < NTOK) {
      #pragma unroll
      for (int n=0;n<4;++n)
        out[(size_t)m*EMB + n0 + 16*n + c] = acc[n][r];
    }
  }
}

// ---------------------------------------------------------------------------
extern "C" void kernel_launch(void* const* d_in, const int* in_sizes, int n_in,
                              void* d_out, int out_size, void* d_ws, size_t ws_size,
                              hipStream_t stream) {
  const float* x   = (const float*)d_in[0];
  const float* qw  = (const float*)d_in[1];
  const float* kw  = (const float*)d_in[2];
  const float* vw  = (const float*)d_in[3];
  const float* qrw = (const float*)d_in[4];
  const float* krw = (const float*)d_in[5];
  const float* ow  = (const float*)d_in[6];
  float* out = (float*)d_out;

  float* ws = (float*)d_ws;
  float* Qb = ws;
  float* Kb = Qb + QSZ;
  float* Vb = Kb + KSZ;
  float* Ab = Vb + VSZ;
  ushort* KhiG = (ushort*)(Ab + ASZ);
  ushort* KloG = KhiG + KPK;
  ushort* VhiT = KloG + KPK;

  // 1. fused projections (MFMA split-4)
  dim3 g1((NTOK + 63)/64, 960/64);            // 65 x 15
  proj_kernel<<<g1, 256, 0, stream>>>(x, qw, kw, vw, qrw, krw, Qb, Kb, Vb);

  // 2. rope on q_r / k_r
  {
    int total = NB*(NH+NKV)*S_LEN;
    rope_kernel<<<(total+255)/256, 256, 0, stream>>>(Qb, Kb);
  }

  // 3. fake-quant K (first 2048) and V (first 2032)
  {
    int kwaves = NB*NKV*32;
    quant_key_kernel<<<(kwaves*64+255)/256, 256, 0, stream>>>(Kb);
    int vwaves = NB*NKV*2032;
    quant_value_kernel<<<(vwaves*64+255)/256, 256, 0, stream>>>(Vb);
  }

  // 4. pack KV (K hi/lo row-major; V hi transposed), zero-padded
  {
    int ksegs = NB*NKV*S_PAD*8;
    pack_k_kernel<<<(ksegs+255)/256, 256, 0, stream>>>(Kb, KhiG, KloG);
    pack_v_kernel<<<NB*NKV*33, 256, 0, stream>>>(Vb, VhiT);
  }

  // 5. causal flash attention (MFMA; QK split-3, PV bf16)
  dim3 ga((S_LEN+63)/64, NB*NH);               // 33 x 18
  attn_kernel<<<ga, 256, 0, stream>>>(Qb, KhiG, KloG, VhiT, Ab);

  // 6. output projection (MFMA, split-bf16)
  dim3 go((NTOK + 63)/64, EMB/64);             // 65 x 9
  oproj_kernel<<<go, 256, 0, stream>>>(Ab, ow, out);
}